// Round 7
// baseline (30.117 us; speedup 1.0000x reference)
//
#include <hip/hip_runtime.h>

// out[i] = A_source[i] + b2 + sum_j W2[j] * tanh(W1[j][0]*c_target[i] + W1[j][1]*wavelength[i] + b1[j])
// (W1[j][2] multiplies a zero; c_source is unused by the reference.)
//
// History: R1 45us (IEEE div VALU-bound) -> R2 28us (exp2+rcp) -> R4/R5 ILP
// ladder regressed (29.8/32.6) -> R6 Pade(4)+quad-batched rcp: VALUBusy
// 52->34% but 27.9us unchanged => memory-system-bound at ~4.6 TB/s effective
// (cold 128MB/replay; harness fills 268MB between replays).
//
// Round 7: dispatch-rate test. Same R6 math; 2048 blocks x 256 threads with a
// grid-stride loop (exactly 4 iters/thread, unroll 1 -> VGPR stays low, 8
// waves/SIMD). Iterations stride 32MB so per-iteration access pattern is
// identical to R6's; only the workgroup count changes (8192 -> 2048).

#define HGEO 8

__global__ __launch_bounds__(256) void geodesic_kernel(
    const float4* __restrict__ c_target,
    const float4* __restrict__ wavelength,
    const float4* __restrict__ A_source,
    const float* __restrict__ W1,   // [8][3] row-major
    const float* __restrict__ b1,   // [8]
    const float* __restrict__ W2,   // [8]
    const float* __restrict__ b2,   // [1]
    float4* __restrict__ out,
    int n4)
{
    // Uniform params -> registers. Fold W2 into the Pade numerator coeffs.
    float wa[HGEO], wb[HGEO], bb[HGEO], n0[HGEO], n1[HGEO];
    const float bias2 = b2[0];
#pragma unroll
    for (int j = 0; j < HGEO; ++j) {
        wa[j] = W1[j * 3 + 0];
        wb[j] = W1[j * 3 + 1];
        bb[j] = b1[j];
        float wo = W2[j];
        n0[j] = 105.0f * wo;
        n1[j] = 10.0f * wo;
    }

    const int stride = gridDim.x * blockDim.x;
#pragma unroll 1
    for (int i = blockIdx.x * blockDim.x + threadIdx.x; i < n4; i += stride) {
        float4 c = c_target[i];
        float4 w = wavelength[i];
        float4 a = A_source[i];

        const float cv[4] = {c.x, c.y, c.z, c.w};
        const float wv[4] = {w.x, w.y, w.z, w.w};
        const float av[4] = {a.x, a.y, a.z, a.w};
        float ov[4];

#pragma unroll
        for (int k = 0; k < 4; ++k) {
            float s = av[k] + bias2;
            float num[HGEO], den[HGEO];
#pragma unroll
            for (int j = 0; j < HGEO; ++j) {
                float z = fmaf(wa[j], cv[k], fmaf(wb[j], wv[k], bb[j]));
                z = fminf(fmaxf(z, -3.2f), 3.2f);            // v_med3_f32
                float u = z * z;
                num[j] = z * fmaf(n1[j], u, n0[j]);          // wo*z*(105+10u)
                den[j] = fmaf(u, u, fmaf(u, 45.0f, 105.0f)); // u^2+45u+105
            }
            // Quad-batched reciprocals: 1 v_rcp per 4 denominators.
#pragma unroll
            for (int g = 0; g < 2; ++g) {
                const int b = g * 4;
                float p01 = den[b + 0] * den[b + 1];
                float p23 = den[b + 2] * den[b + 3];
                float r   = __builtin_amdgcn_rcpf(p01 * p23);
                float r01 = p23 * r;   // 1/(den0*den1)
                float r23 = p01 * r;   // 1/(den2*den3)
                s = fmaf(num[b + 0], den[b + 1] * r01, s);
                s = fmaf(num[b + 1], den[b + 0] * r01, s);
                s = fmaf(num[b + 2], den[b + 3] * r23, s);
                s = fmaf(num[b + 3], den[b + 2] * r23, s);
            }
            ov[k] = s;
        }
        out[i] = make_float4(ov[0], ov[1], ov[2], ov[3]);
    }
}

extern "C" void kernel_launch(void* const* d_in, const int* in_sizes, int n_in,
                              void* d_out, int out_size, void* d_ws, size_t ws_size,
                              hipStream_t stream) {
    // Input order per setup_inputs(): c_source, c_target, wavelength, A_source, W1, b1, W2, b2
    const float4* c_target   = (const float4*)d_in[1];
    const float4* wavelength = (const float4*)d_in[2];
    const float4* A_source   = (const float4*)d_in[3];
    const float*  W1 = (const float*)d_in[4];
    const float*  b1 = (const float*)d_in[5];
    const float*  W2 = (const float*)d_in[6];
    const float*  b2 = (const float*)d_in[7];
    float4* out = (float4*)d_out;

    const int n4 = out_size / 4;     // 2097152 float4s; 4 iters/thread
    const int threads = 256;
    const int blocks = 2048;
    geodesic_kernel<<<blocks, threads, 0, stream>>>(
        c_target, wavelength, A_source, W1, b1, W2, b2, out, n4);
}

// Round 8
// 29.109 us; speedup vs baseline: 1.0346x; 1.0346x over previous
//
#include <hip/hip_runtime.h>

// out[i] = A_source[i] + b2 + sum_j W2[j] * tanh(W1[j][0]*c_target[i] + W1[j][1]*wavelength[i] + b1[j])
// (W1[j][2] multiplies a zero; c_source is unused by the reference.)
//
// History: R1 45us (IEEE div VALU-bound) -> R2 28us (exp2+rcp) -> R4/R5 ILP
// ladder regressed (29.8/32.6; ILP costs ~+2.8us per doubling) -> R6 Pade(4)
// +quad-batched rcp: VALUBusy 52->34% but 27.9us (memory-system-bound) ->
// R7 2048wg grid-stride regressed (30.1) — dispatch rate is not the limit.
// Profiled FETCH=49MB of 96MB input reads => ~half the inputs stay L3-resident
// across replays; our 32MB output store allocates in cache and fights them.
//
// Round 8: R6 exactly + NONTEMPORAL output store (no-allocate write stream;
// keep L3 for the read streams). Single-variable change.

#define HGEO 8

typedef float nfloat4 __attribute__((ext_vector_type(4)));

__global__ __launch_bounds__(256) void geodesic_kernel(
    const float4* __restrict__ c_target,
    const float4* __restrict__ wavelength,
    const float4* __restrict__ A_source,
    const float* __restrict__ W1,   // [8][3] row-major
    const float* __restrict__ b1,   // [8]
    const float* __restrict__ W2,   // [8]
    const float* __restrict__ b2,   // [1]
    float4* __restrict__ out)
{
    // Uniform params -> registers. Fold W2 into the Pade numerator coeffs.
    float wa[HGEO], wb[HGEO], bb[HGEO], n0[HGEO], n1[HGEO];
    const float bias2 = b2[0];
#pragma unroll
    for (int j = 0; j < HGEO; ++j) {
        wa[j] = W1[j * 3 + 0];
        wb[j] = W1[j * 3 + 1];
        bb[j] = b1[j];
        float wo = W2[j];
        n0[j] = 105.0f * wo;
        n1[j] = 10.0f * wo;
    }

    const int i = blockIdx.x * blockDim.x + threadIdx.x;

    float4 c = c_target[i];
    float4 w = wavelength[i];
    float4 a = A_source[i];

    const float cv[4] = {c.x, c.y, c.z, c.w};
    const float wv[4] = {w.x, w.y, w.z, w.w};
    const float av[4] = {a.x, a.y, a.z, a.w};
    float ov[4];

#pragma unroll
    for (int k = 0; k < 4; ++k) {
        float s = av[k] + bias2;
        float num[HGEO], den[HGEO];
#pragma unroll
        for (int j = 0; j < HGEO; ++j) {
            float z = fmaf(wa[j], cv[k], fmaf(wb[j], wv[k], bb[j]));
            z = fminf(fmaxf(z, -3.2f), 3.2f);            // v_med3_f32
            float u = z * z;
            num[j] = z * fmaf(n1[j], u, n0[j]);          // wo*z*(105+10u)
            den[j] = fmaf(u, u, fmaf(u, 45.0f, 105.0f)); // u^2+45u+105
        }
        // Quad-batched reciprocals: 1 v_rcp per 4 denominators.
#pragma unroll
        for (int g = 0; g < 2; ++g) {
            const int b = g * 4;
            float p01 = den[b + 0] * den[b + 1];
            float p23 = den[b + 2] * den[b + 3];
            float r   = __builtin_amdgcn_rcpf(p01 * p23);
            float r01 = p23 * r;   // 1/(den0*den1)
            float r23 = p01 * r;   // 1/(den2*den3)
            s = fmaf(num[b + 0], den[b + 1] * r01, s);
            s = fmaf(num[b + 1], den[b + 0] * r01, s);
            s = fmaf(num[b + 2], den[b + 3] * r23, s);
            s = fmaf(num[b + 3], den[b + 2] * r23, s);
        }
        ov[k] = s;
    }

    nfloat4 o = {ov[0], ov[1], ov[2], ov[3]};
    __builtin_nontemporal_store(o, &((nfloat4*)out)[i]);
}

extern "C" void kernel_launch(void* const* d_in, const int* in_sizes, int n_in,
                              void* d_out, int out_size, void* d_ws, size_t ws_size,
                              hipStream_t stream) {
    // Input order per setup_inputs(): c_source, c_target, wavelength, A_source, W1, b1, W2, b2
    const float4* c_target   = (const float4*)d_in[1];
    const float4* wavelength = (const float4*)d_in[2];
    const float4* A_source   = (const float4*)d_in[3];
    const float*  W1 = (const float*)d_in[4];
    const float*  b1 = (const float*)d_in[5];
    const float*  W2 = (const float*)d_in[6];
    const float*  b2 = (const float*)d_in[7];
    float4* out = (float4*)d_out;

    const int n4 = out_size / 4;     // 2097152 float4s
    const int threads = 256;
    const int blocks = n4 / threads; // 8192 — exact, 1 float4/thread
    geodesic_kernel<<<blocks, threads, 0, stream>>>(
        c_target, wavelength, A_source, W1, b1, W2, b2, out);
}

// Round 9
// 28.408 us; speedup vs baseline: 1.0602x; 1.0247x over previous
//
#include <hip/hip_runtime.h>

// out[i] = A_source[i] + b2 + sum_j W2[j] * tanh(W1[j][0]*c_target[i] + W1[j][1]*wavelength[i] + b1[j])
// (W1[j][2] multiplies a zero; c_source is unused by the reference.)
//
// History: R1 45us (IEEE div VALU-bound) -> R2 28.0us (exp2+rcp) -> R4/R5 ILP
// ladder regressed (29.8/32.6) -> R6 Pade(4)+quad-batched rcp 27.87us
// (VALUBusy 34%, memory-system-bound) -> R7 grid-stride 2048wg 30.1us ->
// R8 NT store 29.1us (write no-allocate regresses; reverted).
// Model: 128MB irreducible @6.3TB/s = 20.3us + ~7us launch/ramp overhead.
//
// Round 9: ramp/tail probe — 1024-thread blocks, 2048 workgroups (4x fewer
// wgs, 2 blocks/CU, identical per-thread work & memory pattern). If neutral,
// the stream is at its practical roofline.

#define HGEO 8

__global__ __launch_bounds__(1024, 2) void geodesic_kernel(
    const float4* __restrict__ c_target,
    const float4* __restrict__ wavelength,
    const float4* __restrict__ A_source,
    const float* __restrict__ W1,   // [8][3] row-major
    const float* __restrict__ b1,   // [8]
    const float* __restrict__ W2,   // [8]
    const float* __restrict__ b2,   // [1]
    float4* __restrict__ out)
{
    // Uniform params -> registers. Fold W2 into the Pade numerator coeffs.
    float wa[HGEO], wb[HGEO], bb[HGEO], n0[HGEO], n1[HGEO];
    const float bias2 = b2[0];
#pragma unroll
    for (int j = 0; j < HGEO; ++j) {
        wa[j] = W1[j * 3 + 0];
        wb[j] = W1[j * 3 + 1];
        bb[j] = b1[j];
        float wo = W2[j];
        n0[j] = 105.0f * wo;
        n1[j] = 10.0f * wo;
    }

    const int i = blockIdx.x * blockDim.x + threadIdx.x;

    float4 c = c_target[i];
    float4 w = wavelength[i];
    float4 a = A_source[i];

    const float cv[4] = {c.x, c.y, c.z, c.w};
    const float wv[4] = {w.x, w.y, w.z, w.w};
    const float av[4] = {a.x, a.y, a.z, a.w};
    float ov[4];

#pragma unroll
    for (int k = 0; k < 4; ++k) {
        float s = av[k] + bias2;
        float num[HGEO], den[HGEO];
#pragma unroll
        for (int j = 0; j < HGEO; ++j) {
            float z = fmaf(wa[j], cv[k], fmaf(wb[j], wv[k], bb[j]));
            z = fminf(fmaxf(z, -3.2f), 3.2f);            // v_med3_f32
            float u = z * z;
            num[j] = z * fmaf(n1[j], u, n0[j]);          // wo*z*(105+10u)
            den[j] = fmaf(u, u, fmaf(u, 45.0f, 105.0f)); // u^2+45u+105
        }
        // Quad-batched reciprocals: 1 v_rcp per 4 denominators.
#pragma unroll
        for (int g = 0; g < 2; ++g) {
            const int b = g * 4;
            float p01 = den[b + 0] * den[b + 1];
            float p23 = den[b + 2] * den[b + 3];
            float r   = __builtin_amdgcn_rcpf(p01 * p23);
            float r01 = p23 * r;   // 1/(den0*den1)
            float r23 = p01 * r;   // 1/(den2*den3)
            s = fmaf(num[b + 0], den[b + 1] * r01, s);
            s = fmaf(num[b + 1], den[b + 0] * r01, s);
            s = fmaf(num[b + 2], den[b + 3] * r23, s);
            s = fmaf(num[b + 3], den[b + 2] * r23, s);
        }
        ov[k] = s;
    }
    out[i] = make_float4(ov[0], ov[1], ov[2], ov[3]);
}

extern "C" void kernel_launch(void* const* d_in, const int* in_sizes, int n_in,
                              void* d_out, int out_size, void* d_ws, size_t ws_size,
                              hipStream_t stream) {
    // Input order per setup_inputs(): c_source, c_target, wavelength, A_source, W1, b1, W2, b2
    const float4* c_target   = (const float4*)d_in[1];
    const float4* wavelength = (const float4*)d_in[2];
    const float4* A_source   = (const float4*)d_in[3];
    const float*  W1 = (const float*)d_in[4];
    const float*  b1 = (const float*)d_in[5];
    const float*  W2 = (const float*)d_in[6];
    const float*  b2 = (const float*)d_in[7];
    float4* out = (float4*)d_out;

    const int n4 = out_size / 4;      // 2097152 float4s
    const int threads = 1024;
    const int blocks = n4 / threads;  // 2048 — exact, 1 float4/thread
    geodesic_kernel<<<blocks, threads, 0, stream>>>(
        c_target, wavelength, A_source, W1, b1, W2, b2, out);
}